// Round 7
// baseline (245.869 us; speedup 1.0000x reference)
//
#include <hip/hip_runtime.h>
#include <float.h>

#define NN 50000
#define NE 800000
#define FD 64
#define NG 64
#define NH (NN * 32)                        // elements per feature-half plane
#define SCAN_B 256
#define NBLK ((NN + SCAN_B - 1) / SCAN_B)   // 196

typedef __attribute__((ext_vector_type(8))) short short8;
typedef __attribute__((ext_vector_type(8))) float float8;
typedef __attribute__((ext_vector_type(4))) float f32x4;

// ---------- bf16 helpers (RNE) ----------
__device__ inline unsigned short f2bf(float f) {
    unsigned u = __float_as_uint(f);
    u += 0x7fffu + ((u >> 16) & 1u);
    return (unsigned short)(u >> 16);
}
__device__ inline float bf2f(unsigned short h) {
    return __uint_as_float(((unsigned)h) << 16);
}

// ---------- monotonic float<->uint encoding for atomic max ----------
__device__ inline unsigned encf(float f) {
    unsigned u = __float_as_uint(f);
    return (u & 0x80000000u) ? ~u : (u | 0x80000000u);
}
__device__ inline float decf(unsigned e) {
    unsigned u = (e & 0x80000000u) ? (e ^ 0x80000000u) : ~e;
    return __uint_as_float(u);
}

// ---------- init: cnt = 0, gmax = enc(-inf) ----------
__global__ void k_init(int* __restrict__ cnt, unsigned* __restrict__ gmax) {
    int i = blockIdx.x * blockDim.x + threadIdx.x;
    if (i < NN) cnt[i] = 0;
    if (i < NG * FD) gmax[i] = encf(-FLT_MAX);
}

__global__ void k_cnt(const int* __restrict__ dst, int* __restrict__ cnt) {
    int i = blockIdx.x * blockDim.x + threadIdx.x;
    if (i < NE) atomicAdd(&cnt[dst[i]], 1);
}

// ---------- scan1 (+ dis folded in) ----------
__global__ void k_scan1(const int* __restrict__ cnt, int* __restrict__ rp,
                        int* __restrict__ bsum, float* __restrict__ dis) {
    __shared__ int tmp[SCAN_B];
    int b = blockIdx.x, t = threadIdx.x;
    int i = b * SCAN_B + t;
    int v = (i < NN) ? cnt[i] : 0;
    if (i < NN) dis[i] = rsqrtf((float)v + 1.0f);   // +1 self loop
    tmp[t] = v;
    __syncthreads();
    for (int off = 1; off < SCAN_B; off <<= 1) {
        int add = (t >= off) ? tmp[t - off] : 0;
        __syncthreads();
        tmp[t] += add;
        __syncthreads();
    }
    if (i < NN) rp[i] = tmp[t] - v;
    if (t == SCAN_B - 1) bsum[b] = tmp[t];
}

__global__ void k_scan2(int* __restrict__ bsum) {
    __shared__ int tmp[256];
    int t = threadIdx.x;
    int v = (t < NBLK) ? bsum[t] : 0;
    tmp[t] = v;
    __syncthreads();
    for (int off = 1; off < 256; off <<= 1) {
        int add = (t >= off) ? tmp[t - off] : 0;
        __syncthreads();
        tmp[t] += add;
        __syncthreads();
    }
    if (t < NBLK) bsum[t] = tmp[t] - v;
}

__global__ void k_scan3(int* __restrict__ rp, const int* __restrict__ bsum,
                        int* __restrict__ cnt) {
    int i = blockIdx.x * blockDim.x + threadIdx.x;
    if (i < NN) {
        rp[i] += bsum[i / SCAN_B];
        cnt[i] = 0;                           // becomes fill cursor
    }
    if (i == 0) rp[NN] = NE;
}

__global__ void k_fill(const int* __restrict__ src, const int* __restrict__ dst,
                       const int* __restrict__ rp, int* __restrict__ cur,
                       int* __restrict__ esrc) {
    int e = blockIdx.x * blockDim.x + threadIdx.x;
    if (e < NE) {
        int d = dst[e];
        int p = rp[d] + atomicAdd(&cur[d], 1);
        esrc[p] = src[e];
    }
}

// ---------- MFMA GEMM: HsB = bf16( dis[r] * (A[r,:] @ W) ), split-plane output ----------
// Plane h holds features [32h, 32h+32) for all rows: HsB[h*NH + r*32 + f'].
// SPLIT_A=1: A f32 (hi/lo split, 3 MFMAs). SPLIT_A=0: A bf16 split-plane (2 MFMAs).
template<int SPLIT_A>
__global__ __launch_bounds__(256) void k_gemm_mfma(const float* __restrict__ Af,
                                                   const unsigned short* __restrict__ Ab,
                                                   const float* __restrict__ W,
                                                   const float* __restrict__ dis,
                                                   unsigned short* __restrict__ HsB) {
    __shared__ unsigned short WtHi[4096];
    __shared__ unsigned short WtLo[4096];
    for (int i = threadIdx.x; i < 4096; i += 256) {
        int k = i >> 6, n = i & 63;
        float w = W[i];                        // W[k][n]
        unsigned short hi = f2bf(w);
        WtHi[n * 64 + k] = hi;
        WtLo[n * 64 + k] = f2bf(w - bf2f(hi));
    }
    __syncthreads();
    int lane = threadIdx.x & 63;
    int m  = lane & 15;    // A-row / D-col
    int kg = lane >> 4;    // k group
    short8 bh[4][2], bl[4][2];
#pragma unroll
    for (int t = 0; t < 4; ++t)
#pragma unroll
        for (int c = 0; c < 2; ++c) {
            int n  = 16 * t + m;
            int k0 = 32 * c + kg * 8;
            bh[t][c] = *(const short8*)&WtHi[n * 64 + k0];
            bl[t][c] = *(const short8*)&WtLo[n * 64 + k0];
        }
    int wid = (blockIdx.x * blockDim.x + threadIdx.x) >> 6;
    int nw  = (gridDim.x * blockDim.x) >> 6;
    for (int tile = wid; tile < NN / 16; tile += nw) {   // NN = 16*3125 exactly
        int r0 = tile * 16;
        f32x4 z = {0.f, 0.f, 0.f, 0.f};
        f32x4 acc0 = z, acc1 = z, acc2 = z, acc3 = z;
#pragma unroll
        for (int c = 0; c < 2; ++c) {
            short8 ah, al;
            if (SPLIT_A) {
                float8 xv = *(const float8*)(Af + (size_t)(r0 + m) * FD + 32 * c + kg * 8);
#pragma unroll
                for (int j = 0; j < 8; ++j) {
                    unsigned short hi = f2bf(xv[j]);
                    ah[j] = (short)hi;
                    al[j] = (short)f2bf(xv[j] - bf2f(hi));
                }
            } else {
                // A stored split-plane bf16: plane c = features 32c..32c+31
                ah = *(const short8*)(Ab + (size_t)c * NH + (size_t)(r0 + m) * 32 + kg * 8);
            }
            acc0 = __builtin_amdgcn_mfma_f32_16x16x32_bf16(ah, bh[0][c], acc0, 0, 0, 0);
            acc0 = __builtin_amdgcn_mfma_f32_16x16x32_bf16(ah, bl[0][c], acc0, 0, 0, 0);
            acc1 = __builtin_amdgcn_mfma_f32_16x16x32_bf16(ah, bh[1][c], acc1, 0, 0, 0);
            acc1 = __builtin_amdgcn_mfma_f32_16x16x32_bf16(ah, bl[1][c], acc1, 0, 0, 0);
            acc2 = __builtin_amdgcn_mfma_f32_16x16x32_bf16(ah, bh[2][c], acc2, 0, 0, 0);
            acc2 = __builtin_amdgcn_mfma_f32_16x16x32_bf16(ah, bl[2][c], acc2, 0, 0, 0);
            acc3 = __builtin_amdgcn_mfma_f32_16x16x32_bf16(ah, bh[3][c], acc3, 0, 0, 0);
            acc3 = __builtin_amdgcn_mfma_f32_16x16x32_bf16(ah, bl[3][c], acc3, 0, 0, 0);
            if (SPLIT_A) {
                acc0 = __builtin_amdgcn_mfma_f32_16x16x32_bf16(al, bh[0][c], acc0, 0, 0, 0);
                acc1 = __builtin_amdgcn_mfma_f32_16x16x32_bf16(al, bh[1][c], acc1, 0, 0, 0);
                acc2 = __builtin_amdgcn_mfma_f32_16x16x32_bf16(al, bh[2][c], acc2, 0, 0, 0);
                acc3 = __builtin_amdgcn_mfma_f32_16x16x32_bf16(al, bh[3][c], acc3, 0, 0, 0);
            }
        }
#pragma unroll
        for (int r = 0; r < 4; ++r) {
            int row = r0 + kg * 4 + r;
            float dd = dis[row];
            size_t b0 = (size_t)row * 32;
            // cols 0-15 (acc0), 16-31 (acc1) -> plane 0; 32-47 (acc2), 48-63 (acc3) -> plane 1
            __builtin_nontemporal_store(f2bf(dd * acc0[r]), HsB + b0 + m);
            __builtin_nontemporal_store(f2bf(dd * acc1[r]), HsB + b0 + 16 + m);
            __builtin_nontemporal_store(f2bf(dd * acc2[r]), HsB + NH + b0 + m);
            __builtin_nontemporal_store(f2bf(dd * acc3[r]), HsB + NH + b0 + 16 + m);
        }
    }
}

// ---------- gather over one feature-half plane ----------
// One wave per node. lanes 0-31 = features of edge j, lanes 32-63 = same features
// of edge j+1 (2 edges per load instruction, combined by shfl_xor(32) at the end).
// v = dis[d] * (Hh[d,:] + sum_s Hh[s,:]) + bias32
// MODE 0: Oh[d,:] = bf16(relu(v))   MODE 1: gmaxh[batch[d]*64 + l] = max(., v)
template<int MODE>
__global__ __launch_bounds__(256) void k_gather_h(const int* __restrict__ rp,
                                                  const int* __restrict__ esrc,
                                                  const float* __restrict__ dis,
                                                  const unsigned short* __restrict__ Hh,
                                                  const float* __restrict__ bias32,
                                                  unsigned short* __restrict__ Oh,
                                                  const int* __restrict__ batch,
                                                  unsigned* __restrict__ gmaxh) {
    int gtid  = blockIdx.x * blockDim.x + threadIdx.x;
    int wave  = gtid >> 6;
    int lane  = threadIdx.x & 63;
    int l     = lane & 31;        // feature within half
    int e     = lane >> 5;        // edge slot parity
    int nwave = (gridDim.x * blockDim.x) >> 6;
    float bb = bias32[l];
    for (int d = wave; d < NN; d += nwave) {
        int beg = rp[d], end = rp[d + 1];
        float a0 = (e == 0) ? bf2f(Hh[(size_t)d * 32 + l]) : 0.f;  // self-loop
        float a1 = 0.f, a2 = 0.f, a3 = 0.f, a4 = 0.f, a5 = 0.f, a6 = 0.f, a7 = 0.f;
        int j = beg;
#define EDGE(K, ACC) { int s = __builtin_nontemporal_load(esrc + j + 2 * (K) + e); \
                       ACC += bf2f(Hh[(size_t)s * 32 + l]); }
        for (; j + 16 <= end; j += 16) {
            EDGE(0, a0) EDGE(1, a1) EDGE(2, a2) EDGE(3, a3)
            EDGE(4, a4) EDGE(5, a5) EDGE(6, a6) EDGE(7, a7)
        }
        if (j + 8 <= end) {
            EDGE(0, a0) EDGE(1, a1) EDGE(2, a2) EDGE(3, a3)
            j += 8;
        }
        if (j + 4 <= end) {
            EDGE(0, a4) EDGE(1, a5)
            j += 4;
        }
        if (j + 2 <= end) {
            EDGE(0, a6)
            j += 2;
        }
        if (j < end && e == 0) {      // odd final edge: slot-0 group only
            int s = esrc[j];
            a7 += bf2f(Hh[(size_t)s * 32 + l]);
        }
#undef EDGE
        float ssum = ((a0 + a1) + (a2 + a3)) + ((a4 + a5) + (a6 + a7));
        ssum += __shfl_xor(ssum, 32);          // combine the two edge groups
        float v = fmaf(dis[d], ssum, bb);
        if (MODE == 0) {
            if (e == 0)
                __builtin_nontemporal_store(f2bf(fmaxf(v, 0.0f)), Oh + (size_t)d * 32 + l);
        } else {
            if (e == 0) atomicMax(&gmaxh[batch[d] * FD + l], encf(v));
        }
    }
}

// ---------- final: out[g,c] = sum_f gmax[g,f] * Wlin[f,c] + blin[c] ----------
__global__ __launch_bounds__(128) void k_final(const unsigned* __restrict__ gmax,
                                               const float* __restrict__ Wlin,
                                               const float* __restrict__ blin,
                                               float* __restrict__ out) {
    __shared__ float G[NG * FD];
    for (int i = threadIdx.x; i < NG * FD; i += 128) G[i] = decf(gmax[i]);
    __syncthreads();
    int t = threadIdx.x;
    int g = t >> 1, c = t & 1;
    float acc = blin[c];
#pragma unroll
    for (int f = 0; f < 64; ++f) acc = fmaf(G[g * 64 + f], Wlin[f * 2 + c], acc);
    out[g * 2 + c] = acc;
}

extern "C" void kernel_launch(void* const* d_in, const int* in_sizes, int n_in,
                              void* d_out, int out_size, void* d_ws, size_t ws_size,
                              hipStream_t stream) {
    const float* x     = (const float*)d_in[0];
    const int*   eidx  = (const int*)d_in[1];
    const int*   batch = (const int*)d_in[2];
    const float* W1    = (const float*)d_in[3];
    const float* b1    = (const float*)d_in[4];
    const float* W2    = (const float*)d_in[5];
    const float* b2    = (const float*)d_in[6];
    const float* Wlin  = (const float*)d_in[7];
    const float* blin  = (const float*)d_in[8];
    float* out = (float*)d_out;

    const int* src = eidx;
    const int* dst = eidx + NE;

    char* ws = (char*)d_ws;
    size_t off = 0;
    auto alloc = [&](size_t bytes) { char* p = ws + off; off += (bytes + 255) & ~size_t(255); return p; };
    int*            cnt  = (int*)alloc(NN * 4);
    float*          dis  = (float*)alloc(NN * 4);
    int*            rp   = (int*)alloc((NN + 1) * 4);
    int*            bsum = (int*)alloc(NBLK * 4);
    int*            esrc = (int*)alloc(NE * 4);                    // 3.2 MB
    unsigned*       gmax = (unsigned*)alloc(NG * FD * 4);
    unsigned short* HsB  = (unsigned short*)alloc((size_t)NN * FD * 2);  // 6.4 MB, 2 planes
    unsigned short* Obf  = (unsigned short*)alloc((size_t)NN * FD * 2);  // 6.4 MB, 2 planes

    const int B = 256;
    const int gN = (NN + B - 1) / B;
    const int gE = (NE + B - 1) / B;
    const int gemmBlocks   = 512;    // 2048 waves
    const int gatherBlocks = 2048;   // 8192 waves

    // ---- CSR build + norm ----
    k_init<<<gN, B, 0, stream>>>(cnt, gmax);
    k_cnt<<<gE, B, 0, stream>>>(dst, cnt);
    k_scan1<<<NBLK, SCAN_B, 0, stream>>>(cnt, rp, bsum, dis);
    k_scan2<<<1, 256, 0, stream>>>(bsum);
    k_scan3<<<gN, B, 0, stream>>>(rp, bsum, cnt);
    k_fill<<<gE, B, 0, stream>>>(src, dst, rp, cnt, esrc);

    // ---- layer 1: HsB = bf16(dis * (x @ W1)) ; Obf = bf16(relu(gather + b1)) ----
    k_gemm_mfma<1><<<gemmBlocks, B, 0, stream>>>(x, nullptr, W1, dis, HsB);
    k_gather_h<0><<<gatherBlocks, B, 0, stream>>>(rp, esrc, dis, HsB,      b1,      Obf,      batch, nullptr);
    k_gather_h<0><<<gatherBlocks, B, 0, stream>>>(rp, esrc, dis, HsB + NH, b1 + 32, Obf + NH, batch, nullptr);

    // ---- layer 2: HsB = bf16(dis * (Obf @ W2)) ; gmax = segmax(gather + b2) ----
    k_gemm_mfma<0><<<gemmBlocks, B, 0, stream>>>(nullptr, Obf, W2, dis, HsB);
    k_gather_h<1><<<gatherBlocks, B, 0, stream>>>(rp, esrc, dis, HsB,      b2,      nullptr, batch, gmax);
    k_gather_h<1><<<gatherBlocks, B, 0, stream>>>(rp, esrc, dis, HsB + NH, b2 + 32, nullptr, batch, gmax + 32);

    // ---- head ----
    k_final<<<1, 128, 0, stream>>>(gmax, Wlin, blin, out);
}